// Round 3
// baseline (247.733 us; speedup 1.0000x reference)
//
#include <hip/hip_runtime.h>
#include <hip/hip_bf16.h>
#include <stdint.h>

// EuclideanDeconf: x[B,D] fp32, W[C,D] fp32 -> out[B,C] fp32
// out = (2/D)*x.W^T - ||x||^2/D - ||w||^2/D
#define B_ROWS 16384
#define D_DIM  1024
#define C_DIM  2048
#define KT32   (D_DIM / 32)    // 32 K-steps of 32 (= pack chunk granularity)
#define MT_TOT (B_ROWS / 16)   // 1024 m-tiles
#define NT_TOT (C_DIM  / 16)   // 128  n-tiles

typedef short bf16x8 __attribute__((ext_vector_type(8)));   // 8 bf16 = 4 VGPRs
typedef float f32x4  __attribute__((ext_vector_type(4)));

#define AS1 __attribute__((address_space(1)))
#define AS3 __attribute__((address_space(3)))
#define BARRIER __builtin_amdgcn_s_barrier()
#define LGKM0 asm volatile("s_waitcnt lgkmcnt(0)")
#define VMCNT(n) asm volatile("s_waitcnt vmcnt(" #n ")" ::: "memory")
#define PRIO1 __builtin_amdgcn_s_setprio(1)
#define PRIO0 __builtin_amdgcn_s_setprio(0)

// ---------------------------------------------------------------------------
// pack_norm (verified R3, unchanged): fp32 -> bf16 in MFMA fragment order.
// Chunk (tile, ktc) = 1 KB = 64 lanes x 16 B; lane l holds row = tile*16+(l&15),
// k = ktc*32 + (l>>4)*8 .. +7 — exact A/B operand layout of
// mfma_f32_16x16x32_bf16. One wave per chunk; norms via atomicAdd.
// ---------------------------------------------------------------------------
__global__ __launch_bounds__(256) void pack_norm(
        const float* __restrict__ x, const float* __restrict__ W,
        ushort* __restrict__ Apk, ushort* __restrict__ Bpk,
        float* __restrict__ x2, float* __restrict__ w2) {
    int chunk = blockIdx.x * 4 + (threadIdx.x >> 6);
    const int lane = threadIdx.x & 63;
    const int XCH = MT_TOT * KT32;              // 32768 x-chunks
    const float* src; ushort* dst; float* norm;
    if (chunk < XCH) { src = x; dst = Apk; norm = x2; }
    else             { src = W; dst = Bpk; norm = w2; chunk -= XCH; }
    const int tile = chunk >> 5;                // /KT32
    const int kt   = chunk & 31;

    const int row = tile * 16 + (lane & 15);
    const int k0  = kt * 32 + (lane >> 4) * 8;
    const float4 v0 = *(const float4*)(src + (size_t)row * D_DIM + k0);
    const float4 v1 = *(const float4*)(src + (size_t)row * D_DIM + k0 + 4);
    float s = v0.x*v0.x + v0.y*v0.y + v0.z*v0.z + v0.w*v0.w
            + v1.x*v1.x + v1.y*v1.y + v1.z*v1.z + v1.w*v1.w;

    ushort u[8]; __hip_bfloat16 h;
    h = __float2bfloat16(v0.x); u[0] = *(const ushort*)&h;
    h = __float2bfloat16(v0.y); u[1] = *(const ushort*)&h;
    h = __float2bfloat16(v0.z); u[2] = *(const ushort*)&h;
    h = __float2bfloat16(v0.w); u[3] = *(const ushort*)&h;
    h = __float2bfloat16(v1.x); u[4] = *(const ushort*)&h;
    h = __float2bfloat16(v1.y); u[5] = *(const ushort*)&h;
    h = __float2bfloat16(v1.z); u[6] = *(const ushort*)&h;
    h = __float2bfloat16(v1.w); u[7] = *(const ushort*)&h;
    *(bf16x8*)(dst + ((size_t)chunk * 64 + lane) * 8) = *(const bf16x8*)u;

    s += __shfl_xor(s, 16, 64);
    s += __shfl_xor(s, 32, 64);
    if (lane < 16) atomicAdd(norm + tile * 16 + lane, s * (1.0f / (float)D_DIM));
}

// ---------------------------------------------------------------------------
// gemm_wide (R6): 128x256 block tile, 4 waves 2x2, WAVE TILE 64x128
// (4mi x 8ni of 16x16x32) -> 12 ds_read_b128 per 32 MFMA (0.375 reads/MFMA,
// was 0.5) because R2's counters put the LDS-read pipe (510 cy/K-step) above
// the MFMA pipe (310 cy). BK=32, TRIPLE-buffered LDS (3 x 24 KB = 72 KB ->
// 2 blocks/CU, 8 waves/CU), counted vmcnt(6) never drained to 0 (T4),
// setprio(1) around the 32-MFMA cluster (T5). Same rotation/barrier
// discipline as R2 (verified): stage kt+2 into the buffer freed at kt-1;
// the wait targets chunks issued one full phase earlier.
// Tail: (kt+2)&31 stages harmless wrapped chunks into never-read buffers.
// XCD slab remap: 8 consecutive wid (all bn of one bm) -> one XCD's L2.
// Epilogue: out = acc*(2/D) - x2[row] - w2[col]  (C/D layout per m89).
// ---------------------------------------------------------------------------
__global__ __launch_bounds__(256, 2) void gemm_wide(
        const ushort* __restrict__ Apk, const ushort* __restrict__ Bpk,
        const float* __restrict__ x2, const float* __restrict__ w2,
        float* __restrict__ out) {
    __shared__ ushort As[3 * 4096];   // 24 KB: 3 bufs x 8 A-tiles x 512
    __shared__ ushort Bs[3 * 8192];   // 48 KB: 3 bufs x 16 B-tiles x 512

    const int tid  = threadIdx.x;
    const int lane = tid & 63;
    const int wv   = tid >> 6;          // [0,4)

    // 1024 blocks; wid consecutive 8 share bm (A panel) -> same XCD L2
    const int wid = (blockIdx.x & 7) * 128 + (blockIdx.x >> 3);
    const int bm  = wid >> 3;           // [0,128): 128-row A panel
    const int bn  = wid & 7;            // [0,8):   256-col B panel

    // staging source bases (ushort units); chunk (tile,ktc) at (tile*KT32+ktc)*512
    const ushort* aSrc = Apk + ((size_t)(bm * 8) * KT32) * 512 + lane * 8;
    const ushort* bSrc = Bpk + ((size_t)(bn * 16) * KT32) * 512 + lane * 8;

    // fragment-read bases (add rotating buffer offset + tile*512 imm at use)
    const ushort* aRd = As + (wv >> 1) * 2048 + lane * 8;   // tiles (wv>>1)*4+mi
    const ushort* bRd = Bs + (wv & 1) * 4096 + lane * 8;    // tiles (wv&1)*8+ni

#define GLL(src, dst) __builtin_amdgcn_global_load_lds( \
        (const AS1 void*)(src), (AS3 void*)(dst), 16, 0, 0)
    // each wave stages A tiles {wv, wv+4} and B tiles {wv, wv+4, wv+8, wv+12}
#define STAGE(ktc, aO, bO) do { \
    GLL(aSrc + ((size_t)(wv)      * KT32 + (ktc)) * 512, As + (aO) + (wv)      * 512); \
    GLL(aSrc + ((size_t)(wv + 4)  * KT32 + (ktc)) * 512, As + (aO) + (wv + 4)  * 512); \
    GLL(bSrc + ((size_t)(wv)      * KT32 + (ktc)) * 512, Bs + (bO) + (wv)      * 512); \
    GLL(bSrc + ((size_t)(wv + 4)  * KT32 + (ktc)) * 512, Bs + (bO) + (wv + 4)  * 512); \
    GLL(bSrc + ((size_t)(wv + 8)  * KT32 + (ktc)) * 512, Bs + (bO) + (wv + 8)  * 512); \
    GLL(bSrc + ((size_t)(wv + 12) * KT32 + (ktc)) * 512, Bs + (bO) + (wv + 12) * 512); \
  } while (0)

    f32x4 acc[4][8];
    #pragma unroll
    for (int mi = 0; mi < 4; ++mi)
        #pragma unroll
        for (int ni = 0; ni < 8; ++ni)
            acc[mi][ni] = (f32x4){0.f, 0.f, 0.f, 0.f};

    // ---- prologue: stage kt=0 -> buf0, kt=1 -> buf1 (12 loads in flight) ----
    STAGE(0, 0, 0);
    STAGE(1, 4096, 8192);
    VMCNT(6);        // kt=0's 6 chunks landed; kt=1's 6 stay in flight
    BARRIER;

    int cA = 0, nA = 4096, sA = 8192;     // rotating A-buffer offsets
    int cB = 0, nB = 8192, sB = 16384;    // rotating B-buffer offsets
    for (int kt = 0; kt < KT32; ++kt) {
        bf16x8 a[4], b[8];
        #pragma unroll
        for (int mi = 0; mi < 4; ++mi)
            a[mi] = *(const bf16x8*)(aRd + cA + mi * 512);
        #pragma unroll
        for (int ni = 0; ni < 8; ++ni)
            b[ni] = *(const bf16x8*)(bRd + cB + ni * 512);

        STAGE((kt + 2) & 31, sA, sB);   // into buffers freed at kt-1

        VMCNT(6);    // kt+1's 6 landed (issued one full phase ago); 6 in flight
        BARRIER;     // all waves' kt+1 chunks visible -> next phase safe
        LGKM0;
        PRIO1;
        #pragma unroll
        for (int mi = 0; mi < 4; ++mi)
            #pragma unroll
            for (int ni = 0; ni < 8; ++ni)
                acc[mi][ni] = __builtin_amdgcn_mfma_f32_16x16x32_bf16(
                    a[mi], b[ni], acc[mi][ni], 0, 0, 0);
        PRIO0;
        BARRIER;     // reads of buf(cur) done before anyone stages into it

        int t = cA; cA = nA; nA = sA; sA = t;
        t = cB; cB = nB; nB = sB; sB = t;
    }

    // ---- epilogue: C/D layout col=lane&15, row=(lane>>4)*4+reg (m89) ----
    const float scale = 2.0f / (float)D_DIM;
    const int rsel = lane & 15;
    const int quad = lane >> 4;
    const int mT0  = bm * 8 + (wv >> 1) * 4;
    const int nT0  = bn * 16 + (wv & 1) * 8;
    const int row0 = mT0 * 16 + quad * 4;
    const int col0 = nT0 * 16 + rsel;

    float x2r[4][4];
    #pragma unroll
    for (int mi = 0; mi < 4; ++mi)
        #pragma unroll
        for (int r = 0; r < 4; ++r)
            x2r[mi][r] = x2[row0 + mi * 16 + r];

    #pragma unroll
    for (int ni = 0; ni < 8; ++ni) {
        const int c = col0 + ni * 16;
        const float wc = w2[c];
        #pragma unroll
        for (int mi = 0; mi < 4; ++mi) {
            #pragma unroll
            for (int r = 0; r < 4; ++r) {
                const int rr = row0 + mi * 16 + r;
                out[(size_t)rr * C_DIM + c] = acc[mi][ni][r] * scale - x2r[mi][r] - wc;
            }
        }
    }
#undef STAGE
#undef GLL
}

// ---------------------------------------------------------------------------
extern "C" void kernel_launch(void* const* d_in, const int* in_sizes, int n_in,
                              void* d_out, int out_size, void* d_ws, size_t ws_size,
                              hipStream_t stream) {
    const float* x = (const float*)d_in[0];   // [B, D] fp32
    const float* W = (const float*)d_in[1];   // [C, D] fp32
    float* out = (float*)d_out;               // [B, C] fp32

    // ws: Apk (32 MB bf16 packed) | Bpk (4 MB) | x2 (64 KB) | w2 (8 KB)
    char* ws = (char*)d_ws;
    ushort* Apk = (ushort*)ws;
    ushort* Bpk = (ushort*)(ws + (size_t)B_ROWS * D_DIM * sizeof(ushort));
    float*  x2  = (float*)(ws + (size_t)(B_ROWS + C_DIM) * D_DIM * sizeof(ushort));
    float*  w2  = x2 + B_ROWS;

    hipMemsetAsync(x2, 0, (B_ROWS + C_DIM) * sizeof(float), stream);

    pack_norm<<<(MT_TOT * KT32 + NT_TOT * KT32) / 4, 256, 0, stream>>>(
        x, W, Apk, Bpk, x2, w2);

    gemm_wide<<<(B_ROWS / 128) * (C_DIM / 256), 256, 0, stream>>>(
        Apk, Bpk, x2, w2, out);
}